// Round 4
// baseline (368.751 us; speedup 1.0000x reference)
//
#include <hip/hip_runtime.h>

#define BATCH 8
#define CH    64
#define HH    112
#define WW    112
#define HW    (HH * WW)          // 12544
#define NP    (BATCH * HW)       // 100352 pixels
#define TAPS  25
#define MIDC  256
#define PIX   64                 // pixels per block (= 1 wave-width group)
#define CPW   16                 // channels per wave (4 waves * 16 = 64)
#define HCPW  8                  // half-channel group for the load pipeline
#define NBLK  (NP / PIX)         // 1568 blocks
#define NXCD  8
#define CPX   (NBLK / NXCD)      // 196 blocks per XCD == blocks per image

// ---------------------------------------------------------------------------
// Kernel A: fold conv2 (1x1, 256->25) into conv1 weights.
//   weff[c][tap][o] = sum_mid w2[o][mid] * w1[mid][c][tap]
//   beff[o]         = b2[o] + sum_mid w2[o][mid] * b1[mid]
// ---------------------------------------------------------------------------
#define WEFF_N (CH * TAPS * TAPS)   // 40000
__global__ __launch_bounds__(256) void weff_kernel(
    const float* __restrict__ w1, const float* __restrict__ b1,
    const float* __restrict__ w2, const float* __restrict__ b2,
    float* __restrict__ weff, float* __restrict__ beff) {
  const int id = blockIdx.x * 256 + threadIdx.x;
  if (id < WEFF_N) {
    const int tap = id % TAPS;
    const int t2  = id / TAPS;
    const int o   = t2 % TAPS;
    const int c   = t2 / TAPS;
    const float* w2o = w2 + o * MIDC;
    float a0 = 0.f, a1 = 0.f;
    #pragma unroll 4
    for (int mid = 0; mid < MIDC; mid += 2) {
      a0 = fmaf(w1[(mid * CH + c) * TAPS + tap],       w2o[mid],     a0);
      a1 = fmaf(w1[((mid + 1) * CH + c) * TAPS + tap], w2o[mid + 1], a1);
    }
    weff[(c * TAPS + tap) * TAPS + o] = a0 + a1;
  } else if (id < WEFF_N + TAPS) {
    const int o = id - WEFF_N;
    const float* w2o = w2 + o * MIDC;
    float b = b2[o];
    for (int mid = 0; mid < MIDC; ++mid) b = fmaf(w2o[mid], b1[mid], b);
    beff[o] = b;
  }
}

// ---------------------------------------------------------------------------
// Kernel B. R4 changes vs R3:
//  - Phase 1 is BRANCH-FREE + software-pipelined: loads unconditional at a
//    clamped/fallback offset, masked to 0 via cndmask afterwards (exact).
//    Two named 8-channel register buffers (xA/xB) alternate so tap t+1's
//    loads always issue under tap t's 400-FMA block.
//  - ONE barrier total: all waves store partials, then every wave
//    redundantly computes softmax into REGISTERS (sfin). Kills two barriers,
//    the wave0-idle section, and phase 2's dynamic LDS weight read.
//  - Phase 2 fully unrolled, branch-free; tap validity folded into sfin=0.
//  - XCD swizzle (image b -> XCD b, L2-resident) retained.
// ---------------------------------------------------------------------------
__global__ __launch_bounds__(256, 6) void picanet_main(
    const float* __restrict__ x, const float* __restrict__ weff,
    const float* __restrict__ beff, float* __restrict__ out) {
  __shared__ float red[4 * PIX * TAPS];       // 25.6 KB -> 6 blocks/CU

  const int lane = threadIdx.x & 63;
  const int wave = threadIdx.x >> 6;
  const int c0 = __builtin_amdgcn_readfirstlane(wave * CPW);

  const int lb = (blockIdx.x & (NXCD - 1)) * CPX + (blockIdx.x >> 3);
  const int p  = lb * PIX + lane;             // NP % 64 == 0, no tail
  const int b  = p / HW;
  const int hw = p % HW;
  const int h  = hw / WW;
  const int w  = hw % WW;

  const float* xb = x + (size_t)b * CH * HW + (size_t)c0 * HW;
  const float* wc = weff + (size_t)c0 * (TAPS * TAPS);

  // ---- Phase 1: pipelined partial logits over this wave's 16 channels ----
  float s[TAPS];
  #pragma unroll
  for (int o = 0; o < TAPS; ++o) s[o] = 0.f;

  float xA[HCPW], xB[HCPW];
  int  offc, offn;
  bool okc, okn;

  // tap 0 offset (i=0,j=0 -> yy=h-4, xx=w-4)
  {
    int yy = h - 4, xx = w - 4;
    okc  = (yy >= 0) & (xx >= 0);             // upper bounds trivially ok
    offc = okc ? (yy * WW + xx) : hw;         // fallback: own pixel (valid)
  }
  #pragma unroll
  for (int c = 0; c < HCPW; ++c) xA[c] = xb[(size_t)c * HW + offc];

  #pragma unroll 1
  for (int t = 0; t < TAPS; ++t) {
    // issue hi-half loads of tap t (covered by lo-half FMAs below)
    #pragma unroll
    for (int c = 0; c < HCPW; ++c) xB[c] = xb[(size_t)(c + HCPW) * HW + offc];

    // FMA lo half (channels c0..c0+7)
    #pragma unroll
    for (int c = 0; c < HCPW; ++c) {
      float xm = okc ? xA[c] : 0.f;
      const float* wp = wc + ((size_t)c * TAPS + t) * TAPS;
      #pragma unroll
      for (int o = 0; o < TAPS; ++o) s[o] = fmaf(xm, wp[o], s[o]);
    }

    // next tap's offset (clamped index on last iter; result unused)
    {
      int tn = (t < TAPS - 1) ? t + 1 : TAPS - 1;
      int i = tn / 5, j = tn % 5;
      int yy = h + 2 * i - 4;
      int xx = w + 2 * j - 4;
      okn  = (yy >= 0) & (yy < HH) & (xx >= 0) & (xx < WW);
      offn = okn ? (yy * WW + xx) : hw;
    }
    // issue lo-half loads of tap t+1 (covered by hi-half FMAs below)
    #pragma unroll
    for (int c = 0; c < HCPW; ++c) xA[c] = xb[(size_t)c * HW + offn];

    // FMA hi half (channels c0+8..c0+15)
    #pragma unroll
    for (int c = 0; c < HCPW; ++c) {
      float xm = okc ? xB[c] : 0.f;
      const float* wp = wc + ((size_t)(c + HCPW) * TAPS + t) * TAPS;
      #pragma unroll
      for (int o = 0; o < TAPS; ++o) s[o] = fmaf(xm, wp[o], s[o]);
    }

    offc = offn; okc = okn;
  }

  // ---- Single barrier: everyone stores partials, everyone reduces ----
  #pragma unroll
  for (int o = 0; o < TAPS; ++o) red[(wave * PIX + lane) * TAPS + o] = s[o];
  __syncthreads();

  // ---- Softmax, computed redundantly by all 4 waves into registers ----
  float m = -1e30f;
  #pragma unroll
  for (int o = 0; o < TAPS; ++o) {
    float v = red[lane * TAPS + o] + red[(PIX + lane) * TAPS + o] +
              red[(2 * PIX + lane) * TAPS + o] +
              red[(3 * PIX + lane) * TAPS + o] + beff[o];
    s[o] = v;
    m = fmaxf(m, v);
  }
  float sum = 0.f;
  #pragma unroll
  for (int o = 0; o < TAPS; ++o) { s[o] = __expf(s[o] - m); sum += s[o]; }
  float inv = 1.f / sum;
  // Scale + fold tap validity: invalid taps contribute 0 in phase 2
  // (denominator keeps all 25 taps, matching the reference softmax).
  #pragma unroll
  for (int o = 0; o < TAPS; ++o) {
    int i = o / 5, j = o % 5;                 // compile-time (unrolled)
    int yy = h + 2 * i - 4;
    int xx = w + 2 * j - 4;
    bool ok = (yy >= 0) & (yy < HH) & (xx >= 0) & (xx < WW);
    s[o] = ok ? s[o] * inv : 0.f;
  }

  // ---- Phase 2: fully unrolled, branch-free weighted gather ----
  float acc[CPW];
  #pragma unroll
  for (int c = 0; c < CPW; ++c) acc[c] = 0.f;

  #pragma unroll
  for (int t = 0; t < TAPS; ++t) {
    int i = t / 5, j = t % 5;                 // compile-time (unrolled)
    int yy = h + 2 * i - 4;
    int xx = w + 2 * j - 4;
    bool ok = (yy >= 0) & (yy < HH) & (xx >= 0) & (xx < WW);
    int offt = ok ? yy * WW + xx : hw;        // sfin == 0 when !ok
    float sv = s[t];                          // static register index
    #pragma unroll
    for (int c = 0; c < CPW; ++c)
      acc[c] = fmaf(sv, xb[(size_t)c * HW + offt], acc[c]);
  }

  float* ob = out + (size_t)b * CH * HW + (size_t)c0 * HW + hw;
  #pragma unroll
  for (int c = 0; c < CPW; ++c) ob[c * HW] = acc[c];
}

extern "C" void kernel_launch(void* const* d_in, const int* in_sizes, int n_in,
                              void* d_out, int out_size, void* d_ws, size_t ws_size,
                              hipStream_t stream) {
  const float* x  = (const float*)d_in[0];
  const float* w1 = (const float*)d_in[1];
  const float* b1 = (const float*)d_in[2];
  const float* w2 = (const float*)d_in[3];
  const float* b2 = (const float*)d_in[4];
  float* out  = (float*)d_out;
  float* weff = (float*)d_ws;                       // 40000 floats
  float* beff = weff + CH * TAPS * TAPS;            // 25 floats

  weff_kernel<<<(WEFF_N + TAPS + 255) / 256, 256, 0, stream>>>(w1, b1, w2, b2, weff, beff);
  picanet_main<<<NBLK, 256, 0, stream>>>(x, weff, beff, out);
}

// Round 5
// 274.433 us; speedup vs baseline: 1.3437x; 1.3437x over previous
//
#include <hip/hip_runtime.h>

#define BATCH 8
#define CH    64
#define HH    112
#define WW    112
#define HW    (HH * WW)          // 12544
#define NP    (BATCH * HW)       // 100352 pixels
#define TAPS  25
#define MIDC  256
#define PIX   64                 // pixels per block (= 1 wave-width group)
#define CPW   16                 // channels per wave (4 waves * 16 = 64)
#define NBLK  (NP / PIX)         // 1568 blocks
#define NXCD  8
#define CPX   (NBLK / NXCD)      // 196 blocks per XCD == blocks per image
#define TILES_PER_IMG (HW / PIX) // 196

// ---------------------------------------------------------------------------
// Kernel A: fold conv2 (1x1, 256->25) into conv1 weights. (unchanged, R3)
// ---------------------------------------------------------------------------
#define WEFF_N (CH * TAPS * TAPS)   // 40000
__global__ __launch_bounds__(256) void weff_kernel(
    const float* __restrict__ w1, const float* __restrict__ b1,
    const float* __restrict__ w2, const float* __restrict__ b2,
    float* __restrict__ weff, float* __restrict__ beff) {
  const int id = blockIdx.x * 256 + threadIdx.x;
  if (id < WEFF_N) {
    const int tap = id % TAPS;
    const int t2  = id / TAPS;
    const int o   = t2 % TAPS;
    const int c   = t2 / TAPS;
    const float* w2o = w2 + o * MIDC;
    float a0 = 0.f, a1 = 0.f;
    #pragma unroll 4
    for (int mid = 0; mid < MIDC; mid += 2) {
      a0 = fmaf(w1[(mid * CH + c) * TAPS + tap],       w2o[mid],     a0);
      a1 = fmaf(w1[((mid + 1) * CH + c) * TAPS + tap], w2o[mid + 1], a1);
    }
    weff[(c * TAPS + tap) * TAPS + o] = a0 + a1;
  } else if (id < WEFF_N + TAPS) {
    const int o = id - WEFF_N;
    const float* w2o = w2 + o * MIDC;
    float b = b2[o];
    for (int mid = 0; mid < MIDC; ++mid) b = fmaf(w2o[mid], b1[mid], b);
    beff[o] = b;
  }
}

// ---------------------------------------------------------------------------
// Kernel T: NCHW -> NHWC transpose of x into workspace.
//   xt[b][hw][c] = x[b][c][hw].  64px x 64ch LDS tile, +1 pad (2-way free).
// ---------------------------------------------------------------------------
__global__ __launch_bounds__(256) void xpose_kernel(
    const float* __restrict__ x, float* __restrict__ xt) {
  __shared__ float tile[CH][PIX + 1];         // 16.6 KB
  const int b  = blockIdx.x / TILES_PER_IMG;
  const int p0 = (blockIdx.x % TILES_PER_IMG) * PIX;
  const int tid = threadIdx.x;
  const int lo = tid & 63;                    // read: pixel ; write: channel
  const int g  = tid >> 6;                    // 0..3
  #pragma unroll
  for (int k = 0; k < 16; ++k) {
    int c = (g << 4) + k;
    tile[c][lo] = x[((size_t)b * CH + c) * HW + p0 + lo];   // coalesced read
  }
  __syncthreads();
  #pragma unroll
  for (int k = 0; k < 16; ++k) {
    int px = (g << 4) + k;
    xt[((size_t)(b * HW + p0 + px)) * CH + lo] = tile[lo][px]; // coalesced write
  }
}

// ---------------------------------------------------------------------------
// Kernel B (NHWC): R3 skeleton, only the x addressing changed.
// Per (lane, tap): 4 x float4 loads (one contiguous 64B run per lane) instead
// of 16 x 4B loads at 49KB stride. 4x fewer vmem instructions / latency slots;
// the per-tap block footprint is one dense ~18KB row window.
// ---------------------------------------------------------------------------
__global__ __launch_bounds__(256, 6) void picanet_nhwc(
    const float* __restrict__ xt, const float* __restrict__ weff,
    const float* __restrict__ beff, float* __restrict__ out) {
  __shared__ float red[2 * PIX * TAPS];       // 12.8 KB

  const int lane = threadIdx.x & 63;
  const int wave = threadIdx.x >> 6;
  const int c0 = __builtin_amdgcn_readfirstlane(wave * CPW);

  // XCD-aware bijective remap: image b pinned to XCD b (3.2 MB < 4 MB L2).
  const int lb = (blockIdx.x & (NXCD - 1)) * CPX + (blockIdx.x >> 3);
  const int p  = lb * PIX + lane;
  const int b  = p / HW;
  const int hw = p % HW;
  const int h  = hw / WW;
  const int w  = hw % WW;

  const float* xb = xt + ((size_t)b * HW) * CH + c0;   // + offt*CH per tap
  const float* wc = weff + (size_t)c0 * (TAPS * TAPS);

  // ---- Phase 1: partial logits over this wave's 16 channels ----
  float s[TAPS];
  #pragma unroll
  for (int o = 0; o < TAPS; ++o) s[o] = 0.f;

  #pragma unroll 1
  for (int tap = 0; tap < TAPS; ++tap) {
    int i = tap / 5, j = tap % 5;
    int yy = h + 2 * i - 4;
    int xx = w + 2 * j - 4;
    if (yy >= 0 && yy < HH && xx >= 0 && xx < WW) {
      const float* xp = xb + (size_t)(yy * WW + xx) * CH;
      float4 q0 = *(const float4*)(xp);
      float4 q1 = *(const float4*)(xp + 4);
      float4 q2 = *(const float4*)(xp + 8);
      float4 q3 = *(const float4*)(xp + 12);
      float xv[CPW];
      xv[0]=q0.x;  xv[1]=q0.y;  xv[2]=q0.z;  xv[3]=q0.w;
      xv[4]=q1.x;  xv[5]=q1.y;  xv[6]=q1.z;  xv[7]=q1.w;
      xv[8]=q2.x;  xv[9]=q2.y;  xv[10]=q2.z; xv[11]=q2.w;
      xv[12]=q3.x; xv[13]=q3.y; xv[14]=q3.z; xv[15]=q3.w;
      const float* wt = wc + tap * TAPS;
      #pragma unroll
      for (int c = 0; c < CPW; ++c) {
        const float* wp = wt + c * (TAPS * TAPS);   // uniform -> scalar loads
        #pragma unroll
        for (int o = 0; o < TAPS; ++o) s[o] = fmaf(xv[c], wp[o], s[o]);
      }
    }
  }

  // ---- Tree reduce across waves (12.8 KB) ----
  if (wave >= 2) {
    float* dst = red + (wave - 2) * (PIX * TAPS);
    #pragma unroll
    for (int o = 0; o < TAPS; ++o) dst[lane * TAPS + o] = s[o];
  }
  __syncthreads();
  if (wave < 2) {
    const float* srcp = red + wave * (PIX * TAPS);
    #pragma unroll
    for (int o = 0; o < TAPS; ++o) s[o] += srcp[lane * TAPS + o];
  }
  if (wave == 1) {
    float* dst = red + (PIX * TAPS);
    #pragma unroll
    for (int o = 0; o < TAPS; ++o) dst[lane * TAPS + o] = s[o];
  }
  __syncthreads();

  // ---- Softmax: full 64-lane wave 0, one pixel per lane ----
  if (wave == 0) {
    const float* srcp = red + (PIX * TAPS);
    float t[TAPS];
    #pragma unroll
    for (int o = 0; o < TAPS; ++o)
      t[o] = s[o] + srcp[lane * TAPS + o] + beff[o];
    float m = t[0];
    #pragma unroll
    for (int o = 1; o < TAPS; ++o) m = fmaxf(m, t[o]);
    float sum = 0.f;
    #pragma unroll
    for (int o = 0; o < TAPS; ++o) { t[o] = __expf(t[o] - m); sum += t[o]; }
    float inv = 1.f / sum;
    #pragma unroll
    for (int o = 0; o < TAPS; ++o) red[lane * TAPS + o] = t[o] * inv;
  }
  __syncthreads();

  // ---- Phase 2: weighted gather (NHWC loads, NCHW stores) ----
  float acc[CPW];
  #pragma unroll
  for (int c = 0; c < CPW; ++c) acc[c] = 0.f;

  #pragma unroll 1
  for (int tap = 0; tap < TAPS; ++tap) {
    int i = tap / 5, j = tap % 5;
    int yy = h + 2 * i - 4;
    int xx = w + 2 * j - 4;
    float sv = red[lane * TAPS + tap];
    if (yy >= 0 && yy < HH && xx >= 0 && xx < WW) {
      const float* xp = xb + (size_t)(yy * WW + xx) * CH;
      float4 q0 = *(const float4*)(xp);
      float4 q1 = *(const float4*)(xp + 4);
      float4 q2 = *(const float4*)(xp + 8);
      float4 q3 = *(const float4*)(xp + 12);
      float xv[CPW];
      xv[0]=q0.x;  xv[1]=q0.y;  xv[2]=q0.z;  xv[3]=q0.w;
      xv[4]=q1.x;  xv[5]=q1.y;  xv[6]=q1.z;  xv[7]=q1.w;
      xv[8]=q2.x;  xv[9]=q2.y;  xv[10]=q2.z; xv[11]=q2.w;
      xv[12]=q3.x; xv[13]=q3.y; xv[14]=q3.z; xv[15]=q3.w;
      #pragma unroll
      for (int c = 0; c < CPW; ++c)
        acc[c] = fmaf(sv, xv[c], acc[c]);
    }
  }

  float* ob = out + (size_t)b * CH * HW + (size_t)c0 * HW + hw;
  #pragma unroll
  for (int c = 0; c < CPW; ++c) ob[c * HW] = acc[c];
}

// ---------------------------------------------------------------------------
// Fallback main kernel (exact R3, NCHW) — used only if ws_size is too small
// for the transposed copy of x.
// ---------------------------------------------------------------------------
__global__ __launch_bounds__(256, 6) void picanet_nchw(
    const float* __restrict__ x, const float* __restrict__ weff,
    const float* __restrict__ beff, float* __restrict__ out) {
  __shared__ float red[2 * PIX * TAPS];

  const int lane = threadIdx.x & 63;
  const int wave = threadIdx.x >> 6;
  const int c0 = __builtin_amdgcn_readfirstlane(wave * CPW);

  const int lb = (blockIdx.x & (NXCD - 1)) * CPX + (blockIdx.x >> 3);
  const int p  = lb * PIX + lane;
  const int b  = p / HW;
  const int hw = p % HW;
  const int h  = hw / WW;
  const int w  = hw % WW;

  const float* xb = x + (size_t)b * CH * HW + (size_t)c0 * HW;
  const float* wc = weff + (size_t)c0 * (TAPS * TAPS);

  float s[TAPS];
  #pragma unroll
  for (int o = 0; o < TAPS; ++o) s[o] = 0.f;

  #pragma unroll 1
  for (int tap = 0; tap < TAPS; ++tap) {
    int i = tap / 5, j = tap % 5;
    int yy = h + 2 * i - 4;
    int xx = w + 2 * j - 4;
    if (yy >= 0 && yy < HH && xx >= 0 && xx < WW) {
      const float* xp = xb + yy * WW + xx;
      float xv[CPW];
      #pragma unroll
      for (int c = 0; c < CPW; ++c) xv[c] = xp[(size_t)c * HW];
      const float* wt = wc + tap * TAPS;
      #pragma unroll
      for (int c = 0; c < CPW; ++c) {
        const float* wp = wt + c * (TAPS * TAPS);
        #pragma unroll
        for (int o = 0; o < TAPS; ++o) s[o] = fmaf(xv[c], wp[o], s[o]);
      }
    }
  }

  if (wave >= 2) {
    float* dst = red + (wave - 2) * (PIX * TAPS);
    #pragma unroll
    for (int o = 0; o < TAPS; ++o) dst[lane * TAPS + o] = s[o];
  }
  __syncthreads();
  if (wave < 2) {
    const float* srcp = red + wave * (PIX * TAPS);
    #pragma unroll
    for (int o = 0; o < TAPS; ++o) s[o] += srcp[lane * TAPS + o];
  }
  if (wave == 1) {
    float* dst = red + (PIX * TAPS);
    #pragma unroll
    for (int o = 0; o < TAPS; ++o) dst[lane * TAPS + o] = s[o];
  }
  __syncthreads();

  if (wave == 0) {
    const float* srcp = red + (PIX * TAPS);
    float t[TAPS];
    #pragma unroll
    for (int o = 0; o < TAPS; ++o)
      t[o] = s[o] + srcp[lane * TAPS + o] + beff[o];
    float m = t[0];
    #pragma unroll
    for (int o = 1; o < TAPS; ++o) m = fmaxf(m, t[o]);
    float sum = 0.f;
    #pragma unroll
    for (int o = 0; o < TAPS; ++o) { t[o] = __expf(t[o] - m); sum += t[o]; }
    float inv = 1.f / sum;
    #pragma unroll
    for (int o = 0; o < TAPS; ++o) red[lane * TAPS + o] = t[o] * inv;
  }
  __syncthreads();

  float acc[CPW];
  #pragma unroll
  for (int c = 0; c < CPW; ++c) acc[c] = 0.f;

  #pragma unroll 1
  for (int tap = 0; tap < TAPS; ++tap) {
    int i = tap / 5, j = tap % 5;
    int yy = h + 2 * i - 4;
    int xx = w + 2 * j - 4;
    float sv = red[lane * TAPS + tap];
    if (yy >= 0 && yy < HH && xx >= 0 && xx < WW) {
      const float* xp = xb + yy * WW + xx;
      #pragma unroll
      for (int c = 0; c < CPW; ++c)
        acc[c] = fmaf(sv, xp[(size_t)c * HW], acc[c]);
    }
  }

  float* ob = out + (size_t)b * CH * HW + (size_t)c0 * HW + hw;
  #pragma unroll
  for (int c = 0; c < CPW; ++c) ob[c * HW] = acc[c];
}

extern "C" void kernel_launch(void* const* d_in, const int* in_sizes, int n_in,
                              void* d_out, int out_size, void* d_ws, size_t ws_size,
                              hipStream_t stream) {
  const float* x  = (const float*)d_in[0];
  const float* w1 = (const float*)d_in[1];
  const float* b1 = (const float*)d_in[2];
  const float* w2 = (const float*)d_in[3];
  const float* b2 = (const float*)d_in[4];
  float* out = (float*)d_out;

  const size_t xt_floats = (size_t)NP * CH;                 // 6.42M floats
  const size_t need = (xt_floats + WEFF_N + TAPS) * sizeof(float);
  const bool nhwc = (ws_size >= need);

  float* xt   = (float*)d_ws;
  float* weff = nhwc ? (xt + xt_floats) : (float*)d_ws;
  float* beff = weff + WEFF_N;

  weff_kernel<<<(WEFF_N + TAPS + 255) / 256, 256, 0, stream>>>(
      w1, b1, w2, b2, weff, beff);
  if (nhwc) {
    xpose_kernel<<<NBLK, 256, 0, stream>>>(x, xt);
    picanet_nhwc<<<NBLK, 256, 0, stream>>>(xt, weff, beff, out);
  } else {
    picanet_nchw<<<NBLK, 256, 0, stream>>>(x, weff, beff, out);
  }
}

// Round 6
// 217.265 us; speedup vs baseline: 1.6972x; 1.2631x over previous
//
#include <hip/hip_runtime.h>

#define BATCH 8
#define CH    64
#define HH    112
#define WW    112
#define HW    (HH * WW)          // 12544
#define NP    (BATCH * HW)       // 100352 pixels
#define TAPS  25
#define MIDC  256
#define PIX   64                 // pixels per block (= 1 wave-width group)
#define CPW   16                 // channels per wave (4 waves * 16 = 64)
#define NBLK  (NP / PIX)         // 1568 blocks
#define NXCD  8
#define CPX   (NBLK / NXCD)      // 196 blocks per XCD == blocks per image

// ---------------------------------------------------------------------------
// Kernel A (R6 rewrite): fold conv2 (1x1, 256->25) into conv1 weights.
//   weff[c][tap][o] = sum_mid w2[o][mid] * w1[mid][c][tap]
//   beff[o]         = b2[o] + sum_mid w2[o][mid] * b1[mid]
// Old version: 157 blocks = 0.6 blocks/CU = 1 wave/SIMD, 256 strided
// L2-latency loads per thread, zero TLP -> latency-serial (the hidden
// ~tens-of-us in total-vs-main). New: 626 blocks (10 waves/CU); each block
// computes 64 outputs; its 4 waves split the K=256 dot into 64-wide chunks;
// 1KB LDS reduce. Per-thread loads 512 -> 128, fully latency-hidden.
// ---------------------------------------------------------------------------
#define WEFF_N   (CH * TAPS * TAPS)   // 40000
#define WEFF_TOT (WEFF_N + TAPS)      // 40025 (beff appended)
__global__ __launch_bounds__(256) void weff_kernel(
    const float* __restrict__ w1, const float* __restrict__ b1,
    const float* __restrict__ w2, const float* __restrict__ b2,
    float* __restrict__ weff, float* __restrict__ beff) {
  __shared__ float part[3][64];              // chunks 1..3 park partials
  const int lane  = threadIdx.x & 63;
  const int chunk = threadIdx.x >> 6;        // mid in [chunk*64, chunk*64+64)
  const int id    = blockIdx.x * 64 + lane;

  float acc = 0.f;
  if (id < WEFF_N) {
    const int tap = id % TAPS;
    const int t2  = id / TAPS;
    const int o   = t2 % TAPS;
    const int c   = t2 / TAPS;
    const float* w2o = w2 + o * MIDC + chunk * 64;
    const float* w1p = w1 + ((size_t)(chunk * 64) * CH + c) * TAPS + tap;
    float a0 = 0.f, a1 = 0.f;
    #pragma unroll 8
    for (int m = 0; m < 64; m += 2) {
      a0 = fmaf(w1p[(size_t)m       * CH * TAPS], w2o[m],     a0);
      a1 = fmaf(w1p[(size_t)(m + 1) * CH * TAPS], w2o[m + 1], a1);
    }
    acc = a0 + a1;
  } else if (id < WEFF_TOT) {
    const int o = id - WEFF_N;
    const float* w2o = w2 + o * MIDC + chunk * 64;
    const float* b1p = b1 + chunk * 64;
    #pragma unroll 8
    for (int m = 0; m < 64; ++m) acc = fmaf(w2o[m], b1p[m], acc);
  }

  if (chunk) part[chunk - 1][lane] = acc;
  __syncthreads();
  if (chunk == 0 && id < WEFF_TOT) {
    float r = acc + part[0][lane] + part[1][lane] + part[2][lane];
    if (id < WEFF_N) {
      const int tap = id % TAPS;
      const int t2  = id / TAPS;
      const int o   = t2 % TAPS;
      const int c   = t2 / TAPS;
      weff[(c * TAPS + tap) * TAPS + o] = r;
    } else {
      beff[id - WEFF_N] = r + b2[id - WEFF_N];
    }
  }
}

// ---------------------------------------------------------------------------
// Kernel B: EXACT R3 main kernel (measured 150 us, VALU 55%) — NCHW,
// lane=pixel coalescing (optimal: 64 lanes x 4B = 4 lines/instr), XCD-pinned
// image-per-L2, 12.8 KB tree reduce, wave0 full-wave softmax.
// ---------------------------------------------------------------------------
__global__ __launch_bounds__(256, 6) void picanet_main(
    const float* __restrict__ x, const float* __restrict__ weff,
    const float* __restrict__ beff, float* __restrict__ out) {
  __shared__ float red[2 * PIX * TAPS];       // 12.8 KB

  const int lane = threadIdx.x & 63;
  const int wave = threadIdx.x >> 6;
  const int c0 = __builtin_amdgcn_readfirstlane(wave * CPW);

  // XCD-aware bijective remap: image b pinned to XCD b (3.2 MB < 4 MB L2).
  const int lb = (blockIdx.x & (NXCD - 1)) * CPX + (blockIdx.x >> 3);
  const int p  = lb * PIX + lane;             // NP % 64 == 0, no tail
  const int b  = p / HW;
  const int hw = p % HW;
  const int h  = hw / WW;
  const int w  = hw % WW;

  const float* xb = x + (size_t)b * CH * HW + (size_t)c0 * HW;
  const float* wc = weff + (size_t)c0 * (TAPS * TAPS);

  // ---- Phase 1: partial logits over this wave's 16 channels ----
  float s[TAPS];
  #pragma unroll
  for (int o = 0; o < TAPS; ++o) s[o] = 0.f;

  #pragma unroll 1
  for (int tap = 0; tap < TAPS; ++tap) {
    int i = tap / 5, j = tap % 5;
    int yy = h + 2 * i - 4;
    int xx = w + 2 * j - 4;
    if (yy >= 0 && yy < HH && xx >= 0 && xx < WW) {
      const float* xp = xb + yy * WW + xx;
      float xv[CPW];
      #pragma unroll
      for (int c = 0; c < CPW; ++c) xv[c] = xp[(size_t)c * HW];
      const float* wt = wc + tap * TAPS;
      #pragma unroll
      for (int c = 0; c < CPW; ++c) {
        const float* wp = wt + c * (TAPS * TAPS);   // uniform -> scalar loads
        #pragma unroll
        for (int o = 0; o < TAPS; ++o) s[o] = fmaf(xv[c], wp[o], s[o]);
      }
    }
  }

  // ---- Tree reduce across waves (12.8 KB) ----
  if (wave >= 2) {
    float* dst = red + (wave - 2) * (PIX * TAPS);
    #pragma unroll
    for (int o = 0; o < TAPS; ++o) dst[lane * TAPS + o] = s[o];
  }
  __syncthreads();
  if (wave < 2) {
    const float* srcp = red + wave * (PIX * TAPS);
    #pragma unroll
    for (int o = 0; o < TAPS; ++o) s[o] += srcp[lane * TAPS + o];
  }
  if (wave == 1) {
    float* dst = red + (PIX * TAPS);
    #pragma unroll
    for (int o = 0; o < TAPS; ++o) dst[lane * TAPS + o] = s[o];
  }
  __syncthreads();

  // ---- Softmax: full 64-lane wave 0, one pixel per lane ----
  if (wave == 0) {
    const float* srcp = red + (PIX * TAPS);
    float t[TAPS];
    #pragma unroll
    for (int o = 0; o < TAPS; ++o)
      t[o] = s[o] + srcp[lane * TAPS + o] + beff[o];
    float m = t[0];
    #pragma unroll
    for (int o = 1; o < TAPS; ++o) m = fmaxf(m, t[o]);
    float sum = 0.f;
    #pragma unroll
    for (int o = 0; o < TAPS; ++o) { t[o] = __expf(t[o] - m); sum += t[o]; }
    float inv = 1.f / sum;
    #pragma unroll
    for (int o = 0; o < TAPS; ++o) red[lane * TAPS + o] = t[o] * inv;
  }
  __syncthreads();

  // ---- Phase 2: out[b,c,h,w] = sum_tap sfin[tap] * x[b,c,tap(h,w)] ----
  float acc[CPW];
  #pragma unroll
  for (int c = 0; c < CPW; ++c) acc[c] = 0.f;

  #pragma unroll 1
  for (int tap = 0; tap < TAPS; ++tap) {
    int i = tap / 5, j = tap % 5;
    int yy = h + 2 * i - 4;
    int xx = w + 2 * j - 4;
    float sv = red[lane * TAPS + tap];
    if (yy >= 0 && yy < HH && xx >= 0 && xx < WW) {
      const float* xp = xb + yy * WW + xx;
      #pragma unroll
      for (int c = 0; c < CPW; ++c)
        acc[c] = fmaf(sv, xp[(size_t)c * HW], acc[c]);
    }
  }

  float* ob = out + (size_t)b * CH * HW + (size_t)c0 * HW + hw;
  #pragma unroll
  for (int c = 0; c < CPW; ++c) ob[c * HW] = acc[c];
}

extern "C" void kernel_launch(void* const* d_in, const int* in_sizes, int n_in,
                              void* d_out, int out_size, void* d_ws, size_t ws_size,
                              hipStream_t stream) {
  const float* x  = (const float*)d_in[0];
  const float* w1 = (const float*)d_in[1];
  const float* b1 = (const float*)d_in[2];
  const float* w2 = (const float*)d_in[3];
  const float* b2 = (const float*)d_in[4];
  float* out  = (float*)d_out;
  float* weff = (float*)d_ws;                       // 40000 floats
  float* beff = weff + WEFF_N;                      // 25 floats

  weff_kernel<<<(WEFF_TOT + 63) / 64, 256, 0, stream>>>(
      w1, b1, w2, b2, weff, beff);
  picanet_main<<<NBLK, 256, 0, stream>>>(x, weff, beff, out);
}